// Round 3
// baseline (808.585 us; speedup 1.0000x reference)
//
#include <hip/hip_runtime.h>

// Problem constants (fixed by setup_inputs: H=W=256, WIN=8, NCAV=2, C=256, HEADS=8)
#define NWIN 2048
#define NT   64
#define CDIM 256
#define NHEAD 8
#define SCALE 0.17677669529663687f   // hd^-0.5 = 1/sqrt(32)

// LDS pitches (elements). Chosen so every wave-wide b128 access hits the
// 8-cycle bank floor: pitch*2B % 128B == 16B  -> 4-bank stride across rows.
#define XP 264     // x / y region row pitch (256 data + 8 pad)
#define QP 40      // q/k slab row pitch (32 data + 8 pad)
#define VP 72      // vT slab row pitch (64 data + 8 pad)
#define HSLAB 7424 // per-head slab elems: q 64*40 + k 64*40 + vT 32*72

typedef short bfrag __attribute__((ext_vector_type(8)));   // 8 bf16 (4 VGPRs)
typedef float f4    __attribute__((ext_vector_type(4)));   // MFMA C/D
typedef unsigned short us4 __attribute__((ext_vector_type(4)));

__device__ __forceinline__ unsigned short f2bf(float f){
  unsigned u = __builtin_bit_cast(unsigned, f);
  u += 0x7FFFu + ((u >> 16) & 1u);       // round-to-nearest-even
  return (unsigned short)(u >> 16);
}

__device__ __forceinline__ f4 mfma16(bfrag a, bfrag b, f4 c){
  return __builtin_amdgcn_mfma_f32_16x16x32_bf16(a, b, c, 0, 0, 0);
}

// ---------------------------------------------------------------------------
// Prep: bf16 W^T (q rows scaled), fused qkv bias, rel_bias transposed [h][j][i],
// ego bias per (window, head).
// ws layout: [0,512K) WT bf16 (1024 out_ch x 256 in_ch; rows 0-255 q*scale,
// 256-511 k, 512-767 v, 768-1023 Wp^T) | [512K,640K) relb f32 [h][j][i]
// | [640K,704K) egob f32 [window][head] | [704K,+3K) bqkv f32 (768)
// ---------------------------------------------------------------------------
__global__ void prep_kernel(const float* __restrict__ aff,
                            const float* __restrict__ Wq,  const float* __restrict__ bq,
                            const float* __restrict__ Wkv, const float* __restrict__ bkv,
                            const float* __restrict__ Wp,
                            const float* __restrict__ relt, const float* __restrict__ egot,
                            unsigned short* __restrict__ wt, float* __restrict__ relb,
                            float* __restrict__ egob, float* __restrict__ bqkv)
{
  const int bid = blockIdx.x, tid = threadIdx.x;
  if (bid < 64) {                         // LDS-tiled coalesced transpose -> bf16
    __shared__ float tile[64][65];
    int R  = (bid >> 2) * 64;             // out_ch block
    int Cb = (bid & 3) * 64;              // in_ch block
    for (int t = 0; t < 16; ++t){
      int idx = t*256 + tid;
      int cl = idx >> 6, rl = idx & 63;   // read coalesced along out_ch
      int r = R + rl, c = Cb + cl;
      float v;
      if (r < 256)      v = Wq[c*256 + r] * SCALE;
      else if (r < 768) v = Wkv[c*512 + (r - 256)];   // k: cols 0..255, v: 256..511
      else              v = Wp[c*256 + (r - 768)];
      tile[cl][rl] = v;
    }
    __syncthreads();
    for (int t = 0; t < 16; ++t){
      int idx = t*256 + tid;
      int rl = idx >> 6, cl = idx & 63;   // write coalesced along in_ch
      wt[(R + rl)*256 + Cb + cl] = f2bf(tile[cl][rl]);
    }
  } else if (bid < 96) {                  // relb transposed: [h][j][i]
    int e0 = (bid - 64)*1024 + tid*4;
    for (int u = 0; u < 4; ++u){
      int e = e0 + u;
      int h = e >> 12, j = (e >> 6) & 63, i = e & 63;
      int yi = i >> 3, xi = i & 7, yj = j >> 3, xj = j & 7;
      int ridx = (yi - yj + 7)*15 + (xi - xj + 7);
      relb[e] = relt[ridx*8 + h];
    }
  } else if (bid == 96) {                 // ego bias
    __shared__ float red[256];
    float ex[2], ey[2];
    for (int cv = 0; cv < 2; ++cv){
      const float* A = aff + cv*6;
      ex[cv] = (A[0] + A[1])*128.0f + A[2];
      ey[cv] = (A[3] + A[4])*128.0f + A[5];
    }
    float dl = 0.0f;
    for (int p = 0; p < 4; ++p){
      int t = p*256 + tid;
      float cx = (float)((t & 31)*8 + 4), cy = (float)((t >> 5)*8 + 4);
      for (int cv = 0; cv < 2; ++cv){
        float dx = cx - ex[cv], dy = cy - ey[cv];
        dl = fmaxf(dl, sqrtf(dx*dx + dy*dy));
      }
    }
    red[tid] = dl; __syncthreads();
    for (int s = 128; s > 0; s >>= 1){
      if (tid < s) red[tid] = fmaxf(red[tid], red[tid + s]);
      __syncthreads();
    }
    float dmax = red[0] + 1e-6f;
    const float PI_F = 3.14159265358979f;
    for (int p = 0; p < 4; ++p){
      int t = p*256 + tid;
      float cx = (float)((t & 31)*8 + 4), cy = (float)((t >> 5)*8 + 4);
      for (int cv = 0; cv < 2; ++cv){
        float dx = cx - ex[cv], dy = cy - ey[cv];
        float d = sqrtf(dx*dx + dy*dy);
        float ang = atan2f(dy, dx);
        int db = (int)(d / dmax * 3.0f);
        int ab = (int)((ang + PI_F) / (2.0f*PI_F) * 3.0f);
        int idx = db*4 + ab;
        int bw = cv*1024 + t;
        for (int h2 = 0; h2 < 8; ++h2)
          egob[bw*8 + h2] = egot[idx*8 + h2];
      }
    }
  } else {                                // fused qkv bias (q part scaled)
    for (int j = tid; j < 768; j += 256)
      bqkv[j] = (j < 256) ? bq[j]*SCALE : bkv[j - 256];
  }
}

// ---------------------------------------------------------------------------
// Persistent fused window attention: 256 blocks (1/CU) x 1024 threads,
// each block loops over 8 windows with register prefetch of the next x tile.
// ---------------------------------------------------------------------------
__global__ __launch_bounds__(1024) void attn_kernel(
    const float* __restrict__ x, const float* __restrict__ wvec,
    const float* __restrict__ bp, float* __restrict__ out,
    const unsigned short* __restrict__ wt, const float* __restrict__ relb,
    const float* __restrict__ egob, const float* __restrict__ bqkv)
{
  __shared__ unsigned short lds_x[20480];   // 40 KiB: x(bf16,pitch XP) -> P chunks -> y
  __shared__ unsigned short lds_qkv[NHEAD*HSLAB]; // 116 KiB padded q/k/vT slabs

  const int tid = threadIdx.x;
  const int wv = tid >> 6, lane = tid & 63;
  const int quad = lane >> 4, cc = lane & 15;
  const int h = wv >> 1, half = wv & 1;

  // softmax of the 2-element blend weights (uniform)
  float w0 = wvec[0], w1 = wvec[1];
  float wm = fmaxf(w0, w1);
  float e0 = __expf(w0 - wm), e1 = __expf(w1 - wm);
  float ws0 = e0/(e0+e1), ws1 = e1/(e0+e1);

  // hoisted window-invariant biases
  const int ob = wv*48;                   // phase-1: 48 out_ch rows per wave
  float bb[3][4];
  #pragma unroll
  for (int mt=0;mt<3;++mt){
    int oc0 = ob + mt*16 + quad*4;
    #pragma unroll
    for (int r2=0;r2<4;++r2) bb[mt][r2] = bqkv[oc0+r2];
  }
  const int mt3 = wv & 3, cbase = (wv >> 2)*64;  // phase-3 tiling
  float bpv[4];
  #pragma unroll
  for (int nt=0;nt<4;++nt) bpv[nt] = bp[cbase + nt*16 + cc];

  int wid = blockIdx.x * 8;
  const float4* xg = (const float4*)x;
  float4 xp[4];
  #pragma unroll
  for (int k=0;k<4;++k) xp[k] = xg[(size_t)wid*4096 + tid + k*1024];

  for (int i = 0; i < 8; ++i, ++wid){
    // ---- stage x (from prefetch regs) -> bf16 LDS, then prefetch next ----
    #pragma unroll
    for (int k=0;k<4;++k){
      int i4 = tid + k*1024;
      int row = i4 >> 6, c4 = i4 & 63;
      float4 v = xp[k];
      us4 pk = { f2bf(v.x), f2bf(v.y), f2bf(v.z), f2bf(v.w) };
      *(us4*)(&lds_x[row*XP + c4*4]) = pk;
    }
    if (i < 7){
      #pragma unroll
      for (int k=0;k<4;++k) xp[k] = xg[(size_t)(wid+1)*4096 + tid + k*1024];
    }
    __syncthreads();

    // ---- phase 1: qkv^T GEMM (A = W^T rows from L2, B = x from LDS) ----
    {
      f4 acc[3][4];
      #pragma unroll
      for (int mt=0;mt<3;++mt)
        #pragma unroll
        for (int nt=0;nt<4;++nt) acc[mt][nt] = (f4){0,0,0,0};
      #pragma unroll
      for (int ks = 0; ks < 8; ++ks){
        bfrag afr[3], bfr[4];
        #pragma unroll
        for (int mt=0;mt<3;++mt)
          afr[mt] = *(const bfrag*)(wt + (ob + mt*16 + cc)*256 + ks*32 + quad*8);
        #pragma unroll
        for (int nt=0;nt<4;++nt)
          bfr[nt] = *(const bfrag*)(&lds_x[(nt*16 + cc)*XP + ks*32 + quad*8]);
        #pragma unroll
        for (int mt=0;mt<3;++mt)
          #pragma unroll
          for (int nt=0;nt<4;++nt)
            acc[mt][nt] = mfma16(afr[mt], bfr[nt], acc[mt][nt]);
      }
      // C frag: col = token = cc, rows = out_ch = oc0 + {0..3}
      #pragma unroll
      for (int mt=0;mt<3;++mt){
        int oc0 = ob + mt*16 + quad*4;
        int part = oc0 >> 8, ch = oc0 & 255;
        int h2 = ch >> 5, d0 = ch & 31;
        #pragma unroll
        for (int nt=0;nt<4;++nt){
          int tok = nt*16 + cc;
          float v0 = acc[mt][nt][0] + bb[mt][0];
          float v1 = acc[mt][nt][1] + bb[mt][1];
          float v2 = acc[mt][nt][2] + bb[mt][2];
          float v3 = acc[mt][nt][3] + bb[mt][3];
          if (part < 2){                  // q,k token-major [tok][d], pitch QP
            unsigned short* sl = &lds_qkv[h2*HSLAB + part*2560];
            us4 pk = { f2bf(v0), f2bf(v1), f2bf(v2), f2bf(v3) };
            *(us4*)(&sl[tok*QP + d0]) = pk;
          } else {                        // v channel-major vT[d][tok], pitch VP
            unsigned short* vt = &lds_qkv[h2*HSLAB + 5120];
            vt[(d0+0)*VP + tok] = f2bf(v0);
            vt[(d0+1)*VP + tok] = f2bf(v1);
            vt[(d0+2)*VP + tok] = f2bf(v2);
            vt[(d0+3)*VP + tok] = f2bf(v3);
          }
        }
      }
    }
    __syncthreads();

    // ---- phase 2: attention. wave -> (head = wv>>1, row-half = wv&1) ----
    f4 yacc[2][2];
    {
      const unsigned short* qs  = &lds_qkv[h*HSLAB];
      const unsigned short* ks_ = qs + 2560;
      const unsigned short* vts = qs + 5120;
      float ego = egob[wid*8 + h];
      const float* rbh = relb + h*4096;   // [j][i] layout

      bfrag bk[4];
      #pragma unroll
      for (int jt=0;jt<4;++jt)
        bk[jt] = *(const bfrag*)(&ks_[(jt*16 + cc)*QP + quad*8]);

      f4 a4[2][4];                        // logits, frag layout (col=j, row=i)
      #pragma unroll
      for (int it=0;it<2;++it){
        bfrag aq = *(const bfrag*)(&qs[(half*32 + it*16 + cc)*QP + quad*8]);
        #pragma unroll
        for (int jt=0;jt<4;++jt){
          f4 z = (f4){0,0,0,0};
          f4 S = mfma16(aq, bk[jt], z);   // K=32 = hd in one MFMA
          f4 rb = *(const f4*)(&rbh[(jt*16 + cc)*64 + half*32 + it*16 + quad*4]);
          a4[it][jt] = S + rb + ego;
        }
      }
      // row stats over 64 cols: 4 jt regs + 16 col-lanes (xor 1,2,4,8)
      float rmax[2][4], rinv[2][4];
      #pragma unroll
      for (int it=0;it<2;++it)
        #pragma unroll
        for (int r=0;r<4;++r){
          float m = fmaxf(fmaxf(a4[it][0][r], a4[it][1][r]),
                          fmaxf(a4[it][2][r], a4[it][3][r]));
          #pragma unroll
          for (int off=1; off<16; off<<=1) m = fmaxf(m, __shfl_xor(m, off, 64));
          float s = __expf(a4[it][0][r]-m) + __expf(a4[it][1][r]-m)
                  + __expf(a4[it][2][r]-m) + __expf(a4[it][3][r]-m);
          #pragma unroll
          for (int off=1; off<16; off<<=1) s += __shfl_xor(s, off, 64);
          rmax[it][r] = m; rinv[it][r] = ws0 / s;   // fold blend weight
        }
      // blended P (C-layout) -> wave-private LDS chunk (pitch QP) -> A-layout
      #pragma unroll
      for (int it=0;it<2;++it)
        #pragma unroll
        for (int nt=0;nt<2;++nt) yacc[it][nt] = (f4){0,0,0,0};
      unsigned short* Pw = &lds_x[wv*1280];  // 32 rows x pitch 40
      #pragma unroll
      for (int chunk=0; chunk<2; ++chunk){
        #pragma unroll
        for (int it=0;it<2;++it)
          #pragma unroll
          for (int jtl=0;jtl<2;++jtl){
            int jt = chunk*2 + jtl;
            #pragma unroll
            for (int r=0;r<4;++r){
              float av = a4[it][jt][r];
              float rl = fmaxf(av, 0.0f);
              float p = rinv[it][r]*__expf(av - rmax[it][r]) + ws1*rl*rl;
              Pw[(it*16 + quad*4 + r)*QP + jtl*16 + cc] = f2bf(p);
            }
          }
        bfrag pa[2], pb[2];
        #pragma unroll
        for (int itl=0;itl<2;++itl)
          pa[itl] = *(const bfrag*)(&Pw[(itl*16 + cc)*QP + quad*8]);
        #pragma unroll
        for (int nt=0;nt<2;++nt)
          pb[nt] = *(const bfrag*)(&vts[(nt*16 + cc)*VP + chunk*32 + quad*8]);
        #pragma unroll
        for (int itl=0;itl<2;++itl)
          #pragma unroll
          for (int nt=0;nt<2;++nt)
            yacc[itl][nt] = mfma16(pa[itl], pb[nt], yacc[itl][nt]);
      }
    }
    __syncthreads();                      // all P reads done before y overwrites lds_x

    // ---- y (64 x 256 bf16, token-major, pitch XP) into lds_x ----
    #pragma unroll
    for (int itl=0;itl<2;++itl)
      #pragma unroll
      for (int nt=0;nt<2;++nt)
        #pragma unroll
        for (int r=0;r<4;++r){
          int ii = half*32 + itl*16 + quad*4 + r;
          lds_x[ii*XP + h*32 + nt*16 + cc] = f2bf(yacc[itl][nt][r]);
        }
    __syncthreads();

    // ---- phase 3: out = y @ Wp + bp ----
    {
      f4 o[4];
      #pragma unroll
      for (int nt=0;nt<4;++nt) o[nt] = (f4){0,0,0,0};
      #pragma unroll
      for (int ks=0; ks<8; ++ks){
        bfrag ay = *(const bfrag*)(&lds_x[(mt3*16 + cc)*XP + ks*32 + quad*8]);
        #pragma unroll
        for (int nt=0;nt<4;++nt){
          bfrag bw = *(const bfrag*)(wt + (768 + cbase + nt*16 + cc)*256 + ks*32 + quad*8);
          o[nt] = mfma16(ay, bw, o[nt]);
        }
      }
      float* og = out + (size_t)wid*(NT*CDIM);
      #pragma unroll
      for (int nt=0;nt<4;++nt){
        int col = cbase + nt*16 + cc;
        #pragma unroll
        for (int r=0;r<4;++r){
          int tok = mt3*16 + quad*4 + r;
          og[tok*256 + col] = o[nt][r] + bpv[nt];
        }
      }
    }
    __syncthreads();                      // protect lds_x before next window's staging
  }
}

extern "C" void kernel_launch(void* const* d_in, const int* in_sizes, int n_in,
                              void* d_out, int out_size, void* d_ws, size_t ws_size,
                              hipStream_t stream)
{
  const float* x    = (const float*)d_in[0];
  const float* aff  = (const float*)d_in[1];
  const float* Wq   = (const float*)d_in[2];
  const float* bq   = (const float*)d_in[3];
  const float* Wkv  = (const float*)d_in[4];
  const float* bkv  = (const float*)d_in[5];
  const float* Wp   = (const float*)d_in[6];
  const float* bp   = (const float*)d_in[7];
  const float* relt = (const float*)d_in[8];
  const float* egot = (const float*)d_in[9];
  const float* w    = (const float*)d_in[10];
  float* out = (float*)d_out;

  char* ws = (char*)d_ws;
  unsigned short* wt = (unsigned short*)ws;       // 512 KiB bf16 W^T
  float* relb = (float*)(ws + 524288);            // 128 KiB [h][j][i]
  float* egob = (float*)(ws + 655360);            //  64 KiB
  float* bqkv = (float*)(ws + 720896);            //   3 KiB

  hipLaunchKernelGGL(prep_kernel, dim3(98), dim3(256), 0, stream,
                     aff, Wq, bq, Wkv, bkv, Wp, relt, egot, wt, relb, egob, bqkv);
  hipLaunchKernelGGL(attn_kernel, dim3(256), dim3(1024), 0, stream,
                     x, w, bp, out, wt, relb, egob, bqkv);
}